// Round 2
// baseline (358.664 us; speedup 1.0000x reference)
//
#include <hip/hip_runtime.h>
#include <hip/hip_bf16.h>

#define NB 4
#define SEQ 1024
#define DM 1024
#define NH 16
#define HD 64
#define QSCALE 0.125f

using f32x4  = __attribute__((ext_vector_type(4))) float;
using bf16x8 = __attribute__((ext_vector_type(8))) short;
using s16x4  = __attribute__((ext_vector_type(4))) short;

__device__ __forceinline__ short f2bf(float x){
  __hip_bfloat16 h = __float2bfloat16(x);
  return *reinterpret_cast<short*>(&h);
}
__device__ __forceinline__ float bf2f(short x){
  __hip_bfloat16 h; *reinterpret_cast<short*>(&h) = x;
  return __bfloat162float(h);
}

// ---------------- fp32 -> bf16 convert ----------------
__global__ void cvt_kernel(const float* __restrict__ in, short* __restrict__ out, int n4){
  int i = blockIdx.x * blockDim.x + threadIdx.x;
  if (i < n4){
    float4 v = reinterpret_cast<const float4*>(in)[i];
    s16x4 o;
    o[0] = f2bf(v.x); o[1] = f2bf(v.y); o[2] = f2bf(v.z); o[3] = f2bf(v.w);
    reinterpret_cast<s16x4*>(out)[i] = o;
  }
}

// ---------------- GEMM: out[m][n] = (sum_k A[m][k]*Bt[n][k] + bias[n]) * scale ----
// MODE 0: bf16 out natural [m][n]; MODE 1: bf16 out v-transposed [b][h][hd][nseq];
// MODE 2: fp32 out natural.
template<int MODE>
__global__ __launch_bounds__(256) void gemm64(const short* __restrict__ A,
    const short* __restrict__ Bt, const float* __restrict__ bias,
    void* __restrict__ out, float scale)
{
  __shared__ short At[64*40];   // BK=32 rows: row=t>>2, off=(t&3)*8 (4 x uint4/row)
  __shared__ short Bs[64*40];
  const int t = threadIdx.x;
  const int w = t >> 6, l = t & 63;
  const int lr = l & 15, lg = l >> 4;
  const int m0 = blockIdx.x * 64, n0 = blockIdx.y * 64;
  const int srow = t >> 2, soff = (t & 3) * 8;
  f32x4 acc[4] = {};
  for (int k0 = 0; k0 < DM; k0 += 32){
    __syncthreads();
    uint4 av = *reinterpret_cast<const uint4*>(A  + (m0 + srow) * DM + k0 + soff);
    uint4 bv = *reinterpret_cast<const uint4*>(Bt + (n0 + srow) * DM + k0 + soff);
    *reinterpret_cast<uint4*>(&At[srow*40 + soff]) = av;
    *reinterpret_cast<uint4*>(&Bs[srow*40 + soff]) = bv;
    __syncthreads();
    bf16x8 af = *reinterpret_cast<const bf16x8*>(&At[(w*16 + lr)*40 + lg*8]);
    #pragma unroll
    for (int tt = 0; tt < 4; ++tt){
      bf16x8 bf = *reinterpret_cast<const bf16x8*>(&Bs[(tt*16 + lr)*40 + lg*8]);
      acc[tt] = __builtin_amdgcn_mfma_f32_16x16x32_bf16(af, bf, acc[tt], 0, 0, 0);
    }
  }
  #pragma unroll
  for (int tt = 0; tt < 4; ++tt){
    int n = n0 + tt*16 + lr;
    float bb = bias[n];
    #pragma unroll
    for (int e = 0; e < 4; ++e){
      int m = m0 + w*16 + lg*4 + e;      // C/D: row = 4*(l>>4)+e, col = l&15  [m89]
      float val = (acc[tt][e] + bb) * scale;
      if (MODE == 0){
        reinterpret_cast<short*>(out)[(size_t)m * DM + n] = f2bf(val);
      } else if (MODE == 1){
        int b = m >> 10, nn = m & 1023, h = n >> 6, hd = n & 63;
        reinterpret_cast<short*>(out)[(((size_t)(b*NH + h)*HD + hd) << 10) + nn] = f2bf(val);
      } else {
        reinterpret_cast<float*>(out)[(size_t)m * DM + n] = val;
      }
    }
  }
}

// ---------------- rel scores: Rs[qc][bh][k] = sum_d qh[b,q,h,d]*rel[q,k,d] -------
__global__ __launch_bounds__(256) void relscore_kernel(const short* __restrict__ qh,
    const float* __restrict__ rel, short* __restrict__ Rs, int chunk0)
{
  __shared__ short At[64*72];   // Qall[q]: [bh][d]  (64 rows x 64 shorts)
  __shared__ short Bs[64*72];   // rel[q]:  [k][d] as bf16
  const int t = threadIdx.x, w = t >> 6, l = t & 63, lr = l & 15, lg = l >> 4;
  const int qc = blockIdx.y, q = chunk0 + qc, k0 = blockIdx.x * 64;
  #pragma unroll
  for (int i = 0; i < 2; ++i){
    int c = t + i*256;
    int row = c >> 3, off = (c & 7) * 8;     // 64-short rows: 8 x uint4 per row
    int b = row >> 4, h = row & 15;
    uint4 v = *reinterpret_cast<const uint4*>(qh + ((size_t)(b*SEQ + q)*NH + h)*HD + off);
    *reinterpret_cast<uint4*>(&At[row*72 + off]) = v;
  }
  #pragma unroll
  for (int i = 0; i < 4; ++i){
    int c = t + i*256;
    int row = c >> 4, off = (c & 15) * 4;    // 64-float rows: 16 x float4 per row
    float4 v = *reinterpret_cast<const float4*>(rel + ((size_t)q*SEQ + k0 + row)*HD + off);
    s16x4 o;
    o[0] = f2bf(v.x); o[1] = f2bf(v.y); o[2] = f2bf(v.z); o[3] = f2bf(v.w);
    *reinterpret_cast<s16x4*>(&Bs[row*72 + off]) = o;
  }
  __syncthreads();
  f32x4 acc[4] = {};
  #pragma unroll
  for (int s = 0; s < 2; ++s){
    bf16x8 af = *reinterpret_cast<const bf16x8*>(&At[(w*16 + lr)*72 + s*32 + lg*8]);
    #pragma unroll
    for (int tt = 0; tt < 4; ++tt){
      bf16x8 bf = *reinterpret_cast<const bf16x8*>(&Bs[(tt*16 + lr)*72 + s*32 + lg*8]);
      acc[tt] = __builtin_amdgcn_mfma_f32_16x16x32_bf16(af, bf, acc[tt], 0, 0, 0);
    }
  }
  #pragma unroll
  for (int tt = 0; tt < 4; ++tt){
    #pragma unroll
    for (int e = 0; e < 4; ++e){
      int bh = w*16 + lg*4 + e;
      int kk = k0 + tt*16 + lr;
      Rs[((size_t)qc*64 + bh)*SEQ + kk] = f2bf(acc[tt][e]);
    }
  }
}

// ---------------- flash attention over k, rel scores added from Rs --------------
__global__ __launch_bounds__(256) void flash_kernel(const short* __restrict__ qh,
    const short* __restrict__ kh, const short* __restrict__ vT,
    const short* __restrict__ Rs, short* __restrict__ ao, int chunk0)
{
  __shared__ short Kt[64*72];
  __shared__ short Vt[64*72];
  __shared__ short Rt[64*72];
  __shared__ short Pt[64*72];
  const int t = threadIdx.x, w = t >> 6, l = t & 63, lr = l & 15, lg = l >> 4;
  const int bh = blockIdx.x, b = bh >> 4, h = bh & 15;
  const int q0 = chunk0 + blockIdx.y * 64;
  const int qc0 = blockIdx.y * 64;
  bf16x8 qf[2];
  {
    const short* qbase = qh + ((size_t)(b*SEQ + (q0 + w*16 + lr))*NH + h)*HD;
    qf[0] = *reinterpret_cast<const bf16x8*>(qbase + lg*8);
    qf[1] = *reinterpret_cast<const bf16x8*>(qbase + 32 + lg*8);
  }
  f32x4 oacc[4] = {};
  float mrow[4], lrow[4];
  #pragma unroll
  for (int e = 0; e < 4; ++e){ mrow[e] = -INFINITY; lrow[e] = 0.f; }
  for (int kt = 0; kt < SEQ/64; ++kt){
    int kbase = kt * 64;
    __syncthreads();
    #pragma unroll
    for (int i = 0; i < 2; ++i){
      int c = t + i*256;
      int row = c >> 3, off = (c & 7) * 8;   // 64-short rows: 8 x uint4 per row
      uint4 kv = *reinterpret_cast<const uint4*>(kh + ((size_t)(b*SEQ + kbase + row)*NH + h)*HD + off);
      *reinterpret_cast<uint4*>(&Kt[row*72 + off]) = kv;
      uint4 vv = *reinterpret_cast<const uint4*>(vT + ((size_t)((b*NH + h)*HD + row))*SEQ + kbase + off);
      *reinterpret_cast<uint4*>(&Vt[row*72 + off]) = vv;
      uint4 rv = *reinterpret_cast<const uint4*>(Rs + ((size_t)(qc0 + row)*64 + bh)*SEQ + kbase + off);
      *reinterpret_cast<uint4*>(&Rt[row*72 + off]) = rv;
    }
    __syncthreads();
    f32x4 sa[4] = {};
    #pragma unroll
    for (int s = 0; s < 2; ++s){
      #pragma unroll
      for (int tt = 0; tt < 4; ++tt){
        bf16x8 bf = *reinterpret_cast<const bf16x8*>(&Kt[(tt*16 + lr)*72 + s*32 + lg*8]);
        sa[tt] = __builtin_amdgcn_mfma_f32_16x16x32_bf16(qf[s], bf, sa[tt], 0, 0, 0);
      }
    }
    #pragma unroll
    for (int tt = 0; tt < 4; ++tt)
      #pragma unroll
      for (int e = 0; e < 4; ++e)
        sa[tt][e] += bf2f(Rt[(w*16 + lg*4 + e)*72 + tt*16 + lr]);
    float pvals[4][4];
    #pragma unroll
    for (int e = 0; e < 4; ++e){
      float rm = fmaxf(fmaxf(sa[0][e], sa[1][e]), fmaxf(sa[2][e], sa[3][e]));
      #pragma unroll
      for (int mm = 1; mm < 16; mm <<= 1)
        rm = fmaxf(rm, __shfl_xor(rm, mm, 16));
      float newm = fmaxf(mrow[e], rm);
      float corr = __expf(mrow[e] - newm);
      float rs = 0.f;
      #pragma unroll
      for (int tt = 0; tt < 4; ++tt){
        float p = __expf(sa[tt][e] - newm);
        pvals[tt][e] = p;
        rs += p;
      }
      #pragma unroll
      for (int mm = 1; mm < 16; mm <<= 1)
        rs += __shfl_xor(rs, mm, 16);
      lrow[e] = lrow[e] * corr + rs;
      mrow[e] = newm;
      #pragma unroll
      for (int tt = 0; tt < 4; ++tt)
        oacc[tt][e] *= corr;
    }
    #pragma unroll
    for (int tt = 0; tt < 4; ++tt)
      #pragma unroll
      for (int e = 0; e < 4; ++e)
        Pt[(w*16 + lg*4 + e)*72 + tt*16 + lr] = f2bf(pvals[tt][e]);
    #pragma unroll
    for (int s = 0; s < 2; ++s){
      bf16x8 pa = *reinterpret_cast<const bf16x8*>(&Pt[(w*16 + lr)*72 + s*32 + lg*8]);
      #pragma unroll
      for (int tt = 0; tt < 4; ++tt){
        bf16x8 vb = *reinterpret_cast<const bf16x8*>(&Vt[(tt*16 + lr)*72 + s*32 + lg*8]);
        oacc[tt] = __builtin_amdgcn_mfma_f32_16x16x32_bf16(pa, vb, oacc[tt], 0, 0, 0);
      }
    }
  }
  #pragma unroll
  for (int tt = 0; tt < 4; ++tt){
    #pragma unroll
    for (int e = 0; e < 4; ++e){
      int q = q0 + w*16 + lg*4 + e;
      int hd = tt*16 + lr;
      float val = oacc[tt][e] / lrow[e];
      ao[((size_t)(b*SEQ + q))*DM + h*HD + hd] = f2bf(val);
    }
  }
}

extern "C" void kernel_launch(void* const* d_in, const int* in_sizes, int n_in,
                              void* d_out, int out_size, void* d_ws, size_t ws_size,
                              hipStream_t stream)
{
  const float* q   = (const float*)d_in[0];
  const float* k   = (const float*)d_in[1];
  const float* v   = (const float*)d_in[2];
  const float* rel = (const float*)d_in[3];
  const float* Wq  = (const float*)d_in[4];
  const float* bq  = (const float*)d_in[5];
  const float* Wk  = (const float*)d_in[6];
  const float* bk  = (const float*)d_in[7];
  const float* Wv  = (const float*)d_in[8];
  const float* bv  = (const float*)d_in[9];
  const float* Wo  = (const float*)d_in[10];
  const float* bo  = (const float*)d_in[11];
  float* out = (float*)d_out;

  char* ws = (char*)d_ws;
  short* qb  = (short*)(ws);
  short* kb  = (short*)(ws + 8388608);
  short* vb  = (short*)(ws + 16777216);
  short* qhb = (short*)(ws + 25165824);
  short* khb = (short*)(ws + 33554432);
  short* vTb = (short*)(ws + 41943040);
  short* aob = (short*)(ws + 50331648);
  short* wqb = (short*)(ws + 58720256);
  short* wkb = (short*)(ws + 60817408);
  short* wvb = (short*)(ws + 62914560);
  short* wob = (short*)(ws + 65011712);
  short* Rs  = (short*)(ws + 67108864);

  int qchunk = 512;
  while (qchunk > 64 && 67108864ull + (size_t)qchunk*64*1024*2 > ws_size) qchunk >>= 1;

  dim3 blk(256);
  {
    int n4 = NB*SEQ*DM/4;
    cvt_kernel<<<dim3(n4/256), blk, 0, stream>>>(q, qb, n4);
    cvt_kernel<<<dim3(n4/256), blk, 0, stream>>>(k, kb, n4);
    cvt_kernel<<<dim3(n4/256), blk, 0, stream>>>(v, vb, n4);
    int w4 = DM*DM/4;
    cvt_kernel<<<dim3(w4/256), blk, 0, stream>>>(Wq, wqb, w4);
    cvt_kernel<<<dim3(w4/256), blk, 0, stream>>>(Wk, wkb, w4);
    cvt_kernel<<<dim3(w4/256), blk, 0, stream>>>(Wv, wvb, w4);
    cvt_kernel<<<dim3(w4/256), blk, 0, stream>>>(Wo, wob, w4);
  }
  dim3 gg(NB*SEQ/64, DM/64);
  gemm64<0><<<gg, blk, 0, stream>>>(qb, wqb, bq, qhb, QSCALE);
  gemm64<0><<<gg, blk, 0, stream>>>(kb, wkb, bk, khb, 1.0f);
  gemm64<1><<<gg, blk, 0, stream>>>(vb, wvb, bv, vTb, 1.0f);
  for (int c0 = 0; c0 < SEQ; c0 += qchunk){
    relscore_kernel<<<dim3(SEQ/64, qchunk), blk, 0, stream>>>(qhb, rel, Rs, c0);
    flash_kernel<<<dim3(NB*NH, qchunk/64), blk, 0, stream>>>(qhb, khb, vTb, Rs, aob, c0);
  }
  gemm64<2><<<gg, blk, 0, stream>>>(aob, wob, bo, out, 1.0f);
}

// Round 3
// 306.851 us; speedup vs baseline: 1.1689x; 1.1689x over previous
//
#include <hip/hip_runtime.h>
#include <hip/hip_bf16.h>

#define NB 4
#define SEQ 1024
#define DM 1024
#define NH 16
#define HD 64
#define QSCALE 0.125f

using f32x4  = __attribute__((ext_vector_type(4))) float;
using bf16x8 = __attribute__((ext_vector_type(8))) short;
using s16x4  = __attribute__((ext_vector_type(4))) short;

__device__ __forceinline__ short f2bf(float x){
  __hip_bfloat16 h = __float2bfloat16(x);
  return *reinterpret_cast<short*>(&h);
}
__device__ __forceinline__ float bf2f(short x){
  __hip_bfloat16 h; *reinterpret_cast<short*>(&h) = x;
  return __bfloat162float(h);
}

// async global->LDS, 16B per lane. LDS dest must be wave-uniform base + lane*16.
__device__ __forceinline__ void gld16(const void* g, void* l){
  __builtin_amdgcn_global_load_lds(
      (const __attribute__((address_space(1))) unsigned int*)g,
      (__attribute__((address_space(3))) unsigned int*)l, 16, 0, 0);
}

// ---------------- fp32 -> bf16 converts (batched) ----------------
__global__ void cvt3(const float* __restrict__ a, const float* __restrict__ b,
                     const float* __restrict__ c, short* __restrict__ oa,
                     short* __restrict__ ob, short* __restrict__ oc, int n4){
  int i = blockIdx.x * blockDim.x + threadIdx.x;
  if (i >= n4) return;
  const float* in; short* out;
  if (blockIdx.y == 0){ in = a; out = oa; }
  else if (blockIdx.y == 1){ in = b; out = ob; }
  else { in = c; out = oc; }
  float4 v = reinterpret_cast<const float4*>(in)[i];
  s16x4 o;
  o[0] = f2bf(v.x); o[1] = f2bf(v.y); o[2] = f2bf(v.z); o[3] = f2bf(v.w);
  reinterpret_cast<s16x4*>(out)[i] = o;
}
__global__ void cvt4(const float* __restrict__ a, const float* __restrict__ b,
                     const float* __restrict__ c, const float* __restrict__ d,
                     short* __restrict__ oa, short* __restrict__ ob,
                     short* __restrict__ oc, short* __restrict__ od, int n4){
  int i = blockIdx.x * blockDim.x + threadIdx.x;
  if (i >= n4) return;
  const float* in; short* out;
  if (blockIdx.y == 0){ in = a; out = oa; }
  else if (blockIdx.y == 1){ in = b; out = ob; }
  else if (blockIdx.y == 2){ in = c; out = oc; }
  else { in = d; out = od; }
  float4 v = reinterpret_cast<const float4*>(in)[i];
  s16x4 o;
  o[0] = f2bf(v.x); o[1] = f2bf(v.y); o[2] = f2bf(v.z); o[3] = f2bf(v.w);
  reinterpret_cast<s16x4*>(out)[i] = o;
}

// ---------------- 128x128 GEMM (m97 structure): C = A @ Bt^T + bias -------------
// A [M][1024], Bt [N][1024] both bf16 K-major. Grid (M/128, N/128), 256 thr.
// MODE 0: bf16 out, bias per col. MODE 1: bf16 out, bias per row. MODE 2: f32 out, bias per col.
template<int MODE>
__global__ __launch_bounds__(256) void gemm128(const short* __restrict__ A,
    const short* __restrict__ Bt, const float* __restrict__ bias,
    void* __restrict__ out, float scale, int ldc)
{
  __shared__ short As[128*32];
  __shared__ short Bs[128*32];
  const int t = threadIdx.x, w = t >> 6, l = t & 63, lr = l & 15, lg = l >> 4;
  const int wr = w >> 1, wc = w & 1;
  const int m0 = blockIdx.x * 128, n0 = blockIdx.y * 128;
  f32x4 acc[4][4] = {};
  for (int k0 = 0; k0 < DM; k0 += 32){
    __syncthreads();
    #pragma unroll
    for (int i = 0; i < 2; ++i){
      int c = i*256 + t, row = c >> 2, sl = c & 3;   // 128 rows x 4 chunks of 16B
      gld16(A  + (size_t)(m0 + row)*DM + k0 + sl*8, &As[c*8]);
      gld16(Bt + (size_t)(n0 + row)*DM + k0 + sl*8, &Bs[c*8]);
    }
    __syncthreads();   // compiler drains vmcnt before barrier
    bf16x8 af[4], bfr[4];
    #pragma unroll
    for (int m = 0; m < 4; ++m)
      af[m] = *reinterpret_cast<const bf16x8*>(&As[(wr*64 + m*16 + lr)*32 + lg*8]);
    #pragma unroll
    for (int n = 0; n < 4; ++n)
      bfr[n] = *reinterpret_cast<const bf16x8*>(&Bs[(wc*64 + n*16 + lr)*32 + lg*8]);
    #pragma unroll
    for (int m = 0; m < 4; ++m)
      #pragma unroll
      for (int n = 0; n < 4; ++n)
        acc[m][n] = __builtin_amdgcn_mfma_f32_16x16x32_bf16(af[m], bfr[n], acc[m][n], 0, 0, 0);
  }
  #pragma unroll
  for (int m = 0; m < 4; ++m){
    int row = m0 + wr*64 + m*16 + lg*4;
    #pragma unroll
    for (int n = 0; n < 4; ++n){
      int col = n0 + wc*64 + n*16 + lr;
      float bc = (MODE == 1) ? 0.f : bias[col];
      #pragma unroll
      for (int e = 0; e < 4; ++e){
        float bb = (MODE == 1) ? bias[row + e] : bc;
        float val = (acc[m][n][e] + bb) * scale;
        if (MODE == 2)
          reinterpret_cast<float*>(out)[(size_t)(row + e)*ldc + col] = val;
        else
          reinterpret_cast<short*>(out)[(size_t)(row + e)*ldc + col] = f2bf(val);
      }
    }
  }
}

// ---------------- rel scores: Rs[qc][bh][k] = sum_d qh[b,q,h,d]*rel[q,k,d] -------
__global__ __launch_bounds__(256) void relscore_kernel(const short* __restrict__ qh,
    const float* __restrict__ rel, short* __restrict__ Rs, int chunk0)
{
  __shared__ short At[64*72];   // [bh][d]  64 rows x 64 shorts (72 pad)
  __shared__ short Bs[64*72];   // [k][d]   rel as bf16
  const int t = threadIdx.x, w = t >> 6, l = t & 63, lr = l & 15, lg = l >> 4;
  const int qc = blockIdx.y, q = chunk0 + qc, k0 = blockIdx.x * 64;
  #pragma unroll
  for (int i = 0; i < 2; ++i){
    int c = t + i*256;
    int row = c >> 3, off = (c & 7) * 8;
    int b = row >> 4, h = row & 15;
    uint4 v = *reinterpret_cast<const uint4*>(qh + ((size_t)(b*SEQ + q)*NH + h)*HD + off);
    *reinterpret_cast<uint4*>(&At[row*72 + off]) = v;
  }
  #pragma unroll
  for (int i = 0; i < 4; ++i){
    int c = t + i*256;
    int row = c >> 4, off = (c & 15) * 4;
    float4 v = *reinterpret_cast<const float4*>(rel + ((size_t)q*SEQ + k0 + row)*HD + off);
    s16x4 o;
    o[0] = f2bf(v.x); o[1] = f2bf(v.y); o[2] = f2bf(v.z); o[3] = f2bf(v.w);
    *reinterpret_cast<s16x4*>(&Bs[row*72 + off]) = o;
  }
  __syncthreads();
  f32x4 acc[4] = {};
  #pragma unroll
  for (int s = 0; s < 2; ++s){
    bf16x8 af = *reinterpret_cast<const bf16x8*>(&At[(w*16 + lr)*72 + s*32 + lg*8]);
    #pragma unroll
    for (int tt = 0; tt < 4; ++tt){
      bf16x8 bf = *reinterpret_cast<const bf16x8*>(&Bs[(tt*16 + lr)*72 + s*32 + lg*8]);
      acc[tt] = __builtin_amdgcn_mfma_f32_16x16x32_bf16(af, bf, acc[tt], 0, 0, 0);
    }
  }
  #pragma unroll
  for (int tt = 0; tt < 4; ++tt){
    #pragma unroll
    for (int e = 0; e < 4; ++e){
      int bh = w*16 + lg*4 + e;
      int kk = k0 + tt*16 + lr;
      Rs[((size_t)qc*64 + bh)*SEQ + kk] = f2bf(acc[tt][e]);
    }
  }
}

// ---------------- flash attention; K/V/R staged via gld16 + XOR swizzle ---------
// LDS tiles are [64 rows][64 shorts] linear; source pre-swizzled slot^=(row&7),
// reads apply the same XOR (rule #21 both-sides swizzle).
__global__ __launch_bounds__(256) void flash_kernel(const short* __restrict__ qh,
    const short* __restrict__ kh, const short* __restrict__ vT,
    const short* __restrict__ Rs, short* __restrict__ ao, int chunk0)
{
  __shared__ short Kt[64*64];
  __shared__ short Vt[64*64];
  __shared__ short Rt[64*64];
  __shared__ short Pt[64*72];
  const int t = threadIdx.x, w = t >> 6, l = t & 63, lr = l & 15, lg = l >> 4;
  const int bh = blockIdx.x, b = bh >> 4, h = bh & 15;
  const int q0 = chunk0 + blockIdx.y * 64;
  const int qc0 = blockIdx.y * 64;
  bf16x8 qf[2];
  {
    const short* qbase = qh + ((size_t)(b*SEQ + (q0 + w*16 + lr))*NH + h)*HD;
    qf[0] = *reinterpret_cast<const bf16x8*>(qbase + lg*8);
    qf[1] = *reinterpret_cast<const bf16x8*>(qbase + 32 + lg*8);
  }
  f32x4 oacc[4] = {};
  float mrow[4], lrow[4];
  #pragma unroll
  for (int e = 0; e < 4; ++e){ mrow[e] = -INFINITY; lrow[e] = 0.f; }
  for (int kt = 0; kt < SEQ/64; ++kt){
    int kbase = kt * 64;
    __syncthreads();
    #pragma unroll
    for (int i = 0; i < 2; ++i){
      int c = i*256 + t, row = c >> 3, sl = c & 7;   // 64 rows x 8 chunks of 16B
      int sc = 8 * (sl ^ (row & 7));                  // inverse-swizzled source col
      gld16(kh + ((size_t)(b*SEQ + kbase + row)*NH + h)*HD + sc, &Kt[c*8]);
      gld16(vT + (size_t)(h*HD + row)*(NB*SEQ) + b*SEQ + kbase + sc, &Vt[c*8]);
      gld16(Rs + ((size_t)(qc0 + row)*64 + bh)*SEQ + kbase + sc, &Rt[c*8]);
    }
    __syncthreads();
    f32x4 sa[4] = {};
    #pragma unroll
    for (int s = 0; s < 2; ++s){
      #pragma unroll
      for (int tt = 0; tt < 4; ++tt){
        int krow = tt*16 + lr;
        bf16x8 kf = *reinterpret_cast<const bf16x8*>(&Kt[krow*64 + 8*((s*4 + lg) ^ (krow & 7))]);
        sa[tt] = __builtin_amdgcn_mfma_f32_16x16x32_bf16(qf[s], kf, sa[tt], 0, 0, 0);
      }
    }
    #pragma unroll
    for (int tt = 0; tt < 4; ++tt)
      #pragma unroll
      for (int e = 0; e < 4; ++e){
        int row = w*16 + lg*4 + e, col = tt*16 + lr;
        sa[tt][e] += bf2f(Rt[row*64 + (col ^ ((row & 7) << 3))]);
      }
    float pvals[4][4];
    #pragma unroll
    for (int e = 0; e < 4; ++e){
      float rm = fmaxf(fmaxf(sa[0][e], sa[1][e]), fmaxf(sa[2][e], sa[3][e]));
      #pragma unroll
      for (int mm = 1; mm < 16; mm <<= 1)
        rm = fmaxf(rm, __shfl_xor(rm, mm, 16));
      float newm = fmaxf(mrow[e], rm);
      float corr = __expf(mrow[e] - newm);
      float rs = 0.f;
      #pragma unroll
      for (int tt = 0; tt < 4; ++tt){
        float p = __expf(sa[tt][e] - newm);
        pvals[tt][e] = p;
        rs += p;
      }
      #pragma unroll
      for (int mm = 1; mm < 16; mm <<= 1)
        rs += __shfl_xor(rs, mm, 16);
      lrow[e] = lrow[e] * corr + rs;
      mrow[e] = newm;
      #pragma unroll
      for (int tt = 0; tt < 4; ++tt)
        oacc[tt][e] *= corr;
    }
    #pragma unroll
    for (int tt = 0; tt < 4; ++tt)
      #pragma unroll
      for (int e = 0; e < 4; ++e)
        Pt[(w*16 + lg*4 + e)*72 + tt*16 + lr] = f2bf(pvals[tt][e]);
    #pragma unroll
    for (int s = 0; s < 2; ++s){
      bf16x8 pa = *reinterpret_cast<const bf16x8*>(&Pt[(w*16 + lr)*72 + s*32 + lg*8]);
      #pragma unroll
      for (int tt = 0; tt < 4; ++tt){
        int vrow = tt*16 + lr;
        bf16x8 vf = *reinterpret_cast<const bf16x8*>(&Vt[vrow*64 + 8*((s*4 + lg) ^ (vrow & 7))]);
        oacc[tt] = __builtin_amdgcn_mfma_f32_16x16x32_bf16(pa, vf, oacc[tt], 0, 0, 0);
      }
    }
  }
  #pragma unroll
  for (int tt = 0; tt < 4; ++tt){
    #pragma unroll
    for (int e = 0; e < 4; ++e){
      int q = q0 + w*16 + lg*4 + e;
      int hd = tt*16 + lr;
      float val = oacc[tt][e] / lrow[e];
      ao[((size_t)(b*SEQ + q))*DM + h*HD + hd] = f2bf(val);
    }
  }
}

extern "C" void kernel_launch(void* const* d_in, const int* in_sizes, int n_in,
                              void* d_out, int out_size, void* d_ws, size_t ws_size,
                              hipStream_t stream)
{
  const float* q   = (const float*)d_in[0];
  const float* k   = (const float*)d_in[1];
  const float* v   = (const float*)d_in[2];
  const float* rel = (const float*)d_in[3];
  const float* Wq  = (const float*)d_in[4];
  const float* bq  = (const float*)d_in[5];
  const float* Wk  = (const float*)d_in[6];
  const float* bk  = (const float*)d_in[7];
  const float* Wv  = (const float*)d_in[8];
  const float* bv  = (const float*)d_in[9];
  const float* Wo  = (const float*)d_in[10];
  const float* bo  = (const float*)d_in[11];
  float* out = (float*)d_out;

  char* ws = (char*)d_ws;
  short* qb  = (short*)(ws);
  short* kb  = (short*)(ws + 8388608);
  short* vb  = (short*)(ws + 16777216);
  short* qhb = (short*)(ws + 25165824);
  short* khb = (short*)(ws + 33554432);
  short* vTb = (short*)(ws + 41943040);   // [1024][4096] = (h*64+hd) x (b*1024+n)
  short* aob = (short*)(ws + 50331648);
  short* wqb = (short*)(ws + 58720256);
  short* wkb = (short*)(ws + 60817408);
  short* wvb = (short*)(ws + 62914560);
  short* wob = (short*)(ws + 65011712);
  short* Rs  = (short*)(ws + 67108864);

  int qchunk = 512;
  while (qchunk > 64 && 67108864ull + (size_t)qchunk*64*1024*2 > ws_size) qchunk >>= 1;

  dim3 blk(256);
  {
    int n4 = NB*SEQ*DM/4;
    cvt3<<<dim3(n4/256, 3), blk, 0, stream>>>(q, k, v, qb, kb, vb, n4);
    int w4 = DM*DM/4;
    cvt4<<<dim3(w4/256, 4), blk, 0, stream>>>(Wq, Wk, Wv, Wo, wqb, wkb, wvb, wob, w4);
  }
  dim3 gp(NB*SEQ/128, DM/128);     // (32, 8)
  gemm128<0><<<gp, blk, 0, stream>>>(qb, wqb, bq, qhb, QSCALE, DM);
  gemm128<0><<<gp, blk, 0, stream>>>(kb, wkb, bk, khb, 1.0f, DM);
  dim3 gv(DM/128, NB*SEQ/128);     // (8, 32): A=Wv rows, B=v tokens -> vT layout
  gemm128<1><<<gv, blk, 0, stream>>>(wvb, vb, bv, vTb, 1.0f, NB*SEQ);
  for (int c0 = 0; c0 < SEQ; c0 += qchunk){
    relscore_kernel<<<dim3(SEQ/64, qchunk), blk, 0, stream>>>(qhb, rel, Rs, c0);
    flash_kernel<<<dim3(NB*NH, qchunk/64), blk, 0, stream>>>(qhb, khb, vTb, Rs, aob, c0);
  }
  gemm128<2><<<gp, blk, 0, stream>>>(aob, wob, bo, out, 1.0f, DM);
}

// Round 4
// 246.610 us; speedup vs baseline: 1.4544x; 1.2443x over previous
//
#include <hip/hip_runtime.h>
#include <hip/hip_bf16.h>

#define NB 4
#define SEQ 1024
#define DM 1024
#define NH 16
#define HD 64
#define QSCALE 0.125f
#define NTOK (NB*SEQ)

using f32x4  = __attribute__((ext_vector_type(4))) float;
using bf16x8 = __attribute__((ext_vector_type(8))) short;
using s16x4  = __attribute__((ext_vector_type(4))) short;

__device__ __forceinline__ short f2bf(float x){
  __hip_bfloat16 h = __float2bfloat16(x);
  return *reinterpret_cast<short*>(&h);
}
__device__ __forceinline__ float bf2f(short x){
  __hip_bfloat16 h; *reinterpret_cast<short*>(&h) = x;
  return __bfloat162float(h);
}

// async global->LDS, 16B per lane; LDS dest = wave-uniform base + lane*16.
__device__ __forceinline__ void gld16(const void* g, void* l){
  __builtin_amdgcn_global_load_lds(
      (const __attribute__((address_space(1))) unsigned int*)g,
      (__attribute__((address_space(3))) unsigned int*)l, 16, 0, 0);
}

// ---------------- fp32 -> bf16 convert, all 7 tensors in one dispatch ----------
__global__ void cvt_all(const float* __restrict__ a0, const float* __restrict__ a1,
                        const float* __restrict__ a2, const float* __restrict__ a3,
                        const float* __restrict__ a4, const float* __restrict__ a5,
                        const float* __restrict__ a6,
                        short* o0, short* o1, short* o2, short* o3,
                        short* o4, short* o5, short* o6, int big4, int small4){
  int i = blockIdx.x * blockDim.x + threadIdx.x;
  int y = blockIdx.y;
  int n4 = (y < 3) ? big4 : small4;
  if (i >= n4) return;
  const float* in; short* out;
  if      (y == 0){ in = a0; out = o0; }
  else if (y == 1){ in = a1; out = o1; }
  else if (y == 2){ in = a2; out = o2; }
  else if (y == 3){ in = a3; out = o3; }
  else if (y == 4){ in = a4; out = o4; }
  else if (y == 5){ in = a5; out = o5; }
  else            { in = a6; out = o6; }
  float4 v = reinterpret_cast<const float4*>(in)[i];
  s16x4 o;
  o[0] = f2bf(v.x); o[1] = f2bf(v.y); o[2] = f2bf(v.z); o[3] = f2bf(v.w);
  reinterpret_cast<s16x4*>(out)[i] = o;
}

// ------------- fused Q/K/V projection GEMMs, m97 structure, grid (32, 24) -------
// which = blockIdx.y>>3.  0: qhb = (qb@Wq^T+bq)*0.125  [tok][dm]
//                         1: khb = (kb@Wk^T+bk)        [tok][dm]
//                         2: vTb = (Wv@vb^T +bv_row)   [dm][tok]  (coalesced vT)
__global__ __launch_bounds__(256) void proj_gemm(
    const short* __restrict__ qb, const short* __restrict__ kb, const short* __restrict__ vb,
    const short* __restrict__ wqb, const short* __restrict__ wkb, const short* __restrict__ wvb,
    const float* __restrict__ bq, const float* __restrict__ bk, const float* __restrict__ bv,
    short* __restrict__ qhb, short* __restrict__ khb, short* __restrict__ vTb)
{
  __shared__ short As[128*32];
  __shared__ short Bs[128*32];
  const int t = threadIdx.x, w = t >> 6, l = t & 63, lr = l & 15, lg = l >> 4;
  const int wr = w >> 1, wc = w & 1;
  const int which = blockIdx.y >> 3;
  const short *A, *Bt;
  int m0, n0;
  if (which == 2){ A = wvb; Bt = vb; m0 = (blockIdx.y & 7)*128; n0 = blockIdx.x*128; }
  else if (which == 1){ A = kb; Bt = wkb; m0 = blockIdx.x*128; n0 = (blockIdx.y & 7)*128; }
  else { A = qb; Bt = wqb; m0 = blockIdx.x*128; n0 = (blockIdx.y & 7)*128; }
  f32x4 acc[4][4] = {};
  for (int k0 = 0; k0 < DM; k0 += 32){
    __syncthreads();
    #pragma unroll
    for (int i = 0; i < 2; ++i){
      int c = i*256 + t, row = c >> 2, sl = c & 3;
      gld16(A  + (size_t)(m0 + row)*DM + k0 + sl*8, &As[c*8]);
      gld16(Bt + (size_t)(n0 + row)*DM + k0 + sl*8, &Bs[c*8]);
    }
    __syncthreads();
    bf16x8 af[4], bfr[4];
    #pragma unroll
    for (int m = 0; m < 4; ++m)
      af[m] = *reinterpret_cast<const bf16x8*>(&As[(wr*64 + m*16 + lr)*32 + lg*8]);
    #pragma unroll
    for (int n = 0; n < 4; ++n)
      bfr[n] = *reinterpret_cast<const bf16x8*>(&Bs[(wc*64 + n*16 + lr)*32 + lg*8]);
    #pragma unroll
    for (int m = 0; m < 4; ++m)
      #pragma unroll
      for (int n = 0; n < 4; ++n)
        acc[m][n] = __builtin_amdgcn_mfma_f32_16x16x32_bf16(af[m], bfr[n], acc[m][n], 0, 0, 0);
  }
  #pragma unroll
  for (int m = 0; m < 4; ++m){
    int row = m0 + wr*64 + m*16 + lg*4;
    #pragma unroll
    for (int n = 0; n < 4; ++n){
      int col = n0 + wc*64 + n*16 + lr;
      #pragma unroll
      for (int e = 0; e < 4; ++e){
        if (which == 0)
          qhb[(size_t)(row + e)*DM + col] = f2bf((acc[m][n][e] + bq[col]) * QSCALE);
        else if (which == 1)
          khb[(size_t)(row + e)*DM + col] = f2bf(acc[m][n][e] + bk[col]);
        else
          vTb[(size_t)(row + e)*NTOK + col] = f2bf(acc[m][n][e] + bv[row + e]);
      }
    }
  }
}

// ------------- out GEMM: out = aob @ Wo^T + bo, fp32 out, grid (32, 8) ----------
__global__ __launch_bounds__(256) void out_gemm(const short* __restrict__ A,
    const short* __restrict__ Bt, const float* __restrict__ bias, float* __restrict__ out)
{
  __shared__ short As[128*32];
  __shared__ short Bs[128*32];
  const int t = threadIdx.x, w = t >> 6, l = t & 63, lr = l & 15, lg = l >> 4;
  const int wr = w >> 1, wc = w & 1;
  const int m0 = blockIdx.x*128, n0 = blockIdx.y*128;
  f32x4 acc[4][4] = {};
  for (int k0 = 0; k0 < DM; k0 += 32){
    __syncthreads();
    #pragma unroll
    for (int i = 0; i < 2; ++i){
      int c = i*256 + t, row = c >> 2, sl = c & 3;
      gld16(A  + (size_t)(m0 + row)*DM + k0 + sl*8, &As[c*8]);
      gld16(Bt + (size_t)(n0 + row)*DM + k0 + sl*8, &Bs[c*8]);
    }
    __syncthreads();
    bf16x8 af[4], bfr[4];
    #pragma unroll
    for (int m = 0; m < 4; ++m)
      af[m] = *reinterpret_cast<const bf16x8*>(&As[(wr*64 + m*16 + lr)*32 + lg*8]);
    #pragma unroll
    for (int n = 0; n < 4; ++n)
      bfr[n] = *reinterpret_cast<const bf16x8*>(&Bs[(wc*64 + n*16 + lr)*32 + lg*8]);
    #pragma unroll
    for (int m = 0; m < 4; ++m)
      #pragma unroll
      for (int n = 0; n < 4; ++n)
        acc[m][n] = __builtin_amdgcn_mfma_f32_16x16x32_bf16(af[m], bfr[n], acc[m][n], 0, 0, 0);
  }
  #pragma unroll
  for (int m = 0; m < 4; ++m){
    int row = m0 + wr*64 + m*16 + lg*4;
    #pragma unroll
    for (int n = 0; n < 4; ++n){
      int col = n0 + wc*64 + n*16 + lr;
      float bb = bias[col];
      #pragma unroll
      for (int e = 0; e < 4; ++e)
        out[(size_t)(row + e)*DM + col] = acc[m][n][e] + bb;
    }
  }
}

// ------------- rel scores: Rs[q][bh][k] = sum_d qh[b,q,h,d]*rel[q,k,d] ----------
// One block per q; qh tile staged once; loops 16 k-tiles of 64.
__global__ __launch_bounds__(256) void relscore2(const short* __restrict__ qh,
    const float* __restrict__ rel, short* __restrict__ Rs)
{
  __shared__ short At[64*72];   // [bh][d]
  __shared__ short Bs[64*72];   // [k][d] bf16
  const int t = threadIdx.x, w = t >> 6, l = t & 63, lr = l & 15, lg = l >> 4;
  const int q = blockIdx.x;
  #pragma unroll
  for (int i = 0; i < 2; ++i){
    int c = t + i*256;
    int row = c >> 3, off = (c & 7) * 8;
    int b = row >> 4, h = row & 15;
    uint4 v = *reinterpret_cast<const uint4*>(qh + ((size_t)(b*SEQ + q)*NH + h)*HD + off);
    *reinterpret_cast<uint4*>(&At[row*72 + off]) = v;
  }
  __syncthreads();
  bf16x8 af[2];
  af[0] = *reinterpret_cast<const bf16x8*>(&At[(w*16 + lr)*72 + lg*8]);
  af[1] = *reinterpret_cast<const bf16x8*>(&At[(w*16 + lr)*72 + 32 + lg*8]);
  for (int k0 = 0; k0 < SEQ; k0 += 64){
    __syncthreads();
    #pragma unroll
    for (int i = 0; i < 4; ++i){
      int c = t + i*256;
      int row = c >> 4, off = (c & 15) * 4;
      float4 v = *reinterpret_cast<const float4*>(rel + ((size_t)q*SEQ + k0 + row)*HD + off);
      s16x4 o;
      o[0] = f2bf(v.x); o[1] = f2bf(v.y); o[2] = f2bf(v.z); o[3] = f2bf(v.w);
      *reinterpret_cast<s16x4*>(&Bs[row*72 + off]) = o;
    }
    __syncthreads();
    f32x4 acc[4] = {};
    #pragma unroll
    for (int s = 0; s < 2; ++s){
      #pragma unroll
      for (int tt = 0; tt < 4; ++tt){
        bf16x8 bf = *reinterpret_cast<const bf16x8*>(&Bs[(tt*16 + lr)*72 + s*32 + lg*8]);
        acc[tt] = __builtin_amdgcn_mfma_f32_16x16x32_bf16(af[s], bf, acc[tt], 0, 0, 0);
      }
    }
    #pragma unroll
    for (int tt = 0; tt < 4; ++tt){
      #pragma unroll
      for (int e = 0; e < 4; ++e){
        int bh = w*16 + lg*4 + e;
        Rs[((size_t)q*64 + bh)*SEQ + k0 + tt*16 + lr] = f2bf(acc[tt][e]);
      }
    }
  }
}

// ------------- flash (no max-sub): KVBLK=128, R direct from global --------------
__global__ __launch_bounds__(256) void flash2(const short* __restrict__ qh,
    const short* __restrict__ kh, const short* __restrict__ vT,
    const short* __restrict__ Rs, short* __restrict__ ao)
{
  __shared__ short Kt[128*64];   // [k][d]  slot^(row&7) swizzle
  __shared__ short Vt[64*128];   // [hd][k] slot^(row&15) swizzle
  __shared__ short Pt[64*136];   // [q][k] pad
  const int t = threadIdx.x, w = t >> 6, l = t & 63, lr = l & 15, lg = l >> 4;
  const int bh = blockIdx.x, b = bh >> 4, h = bh & 15;
  const int q0 = blockIdx.y * 64;
  bf16x8 qf[2];
  {
    const short* qbase = qh + ((size_t)(b*SEQ + (q0 + w*16 + lr))*NH + h)*HD;
    qf[0] = *reinterpret_cast<const bf16x8*>(qbase + lg*8);
    qf[1] = *reinterpret_cast<const bf16x8*>(qbase + 32 + lg*8);
  }
  f32x4 oacc[4] = {};
  float lrow[4] = {0.f, 0.f, 0.f, 0.f};
  for (int kt = 0; kt < SEQ/128; ++kt){
    const int kbase = kt * 128;
    __syncthreads();
    #pragma unroll
    for (int i = 0; i < 4; ++i){      // K: 128 rows x 8 slots of 8 shorts
      int c = i*256 + t, row = c >> 3, sl = c & 7;
      gld16(kh + (size_t)(b*SEQ + kbase + row)*DM + h*HD + 8*(sl ^ (row & 7)), &Kt[c*8]);
    }
    #pragma unroll
    for (int i = 0; i < 4; ++i){      // V: 64 rows x 16 slots
      int c = i*256 + t, row = c >> 4, sl = c & 15;
      gld16(vT + (size_t)(h*HD + row)*NTOK + b*SEQ + kbase + 8*(sl ^ (row & 15)), &Vt[c*8]);
    }
    // R directly into accumulator layout (C-layout scalar loads, 32B coalesced)
    f32x4 sa[8];
    #pragma unroll
    for (int tt = 0; tt < 8; ++tt)
      #pragma unroll
      for (int e = 0; e < 4; ++e){
        int row = q0 + w*16 + lg*4 + e;
        sa[tt][e] = bf2f(Rs[((size_t)row*64 + bh)*SEQ + kbase + tt*16 + lr]);
      }
    __syncthreads();
    #pragma unroll
    for (int s = 0; s < 2; ++s)
      #pragma unroll
      for (int tt = 0; tt < 8; ++tt){
        int krow = tt*16 + lr;
        bf16x8 kf = *reinterpret_cast<const bf16x8*>(&Kt[krow*64 + 8*((s*4 + lg) ^ (krow & 7))]);
        sa[tt] = __builtin_amdgcn_mfma_f32_16x16x32_bf16(qf[s], kf, sa[tt], 0, 0, 0);
      }
    float rs_[4] = {0.f, 0.f, 0.f, 0.f};
    #pragma unroll
    for (int tt = 0; tt < 8; ++tt)
      #pragma unroll
      for (int e = 0; e < 4; ++e){
        float p = __expf(sa[tt][e]);
        rs_[e] += p;
        Pt[(w*16 + lg*4 + e)*136 + tt*16 + lr] = f2bf(p);
      }
    #pragma unroll
    for (int e = 0; e < 4; ++e){
      #pragma unroll
      for (int mm = 1; mm < 16; mm <<= 1)
        rs_[e] += __shfl_xor(rs_[e], mm, 16);
      lrow[e] += rs_[e];
    }
    #pragma unroll
    for (int ks = 0; ks < 4; ++ks){
      bf16x8 pa = *reinterpret_cast<const bf16x8*>(&Pt[(w*16 + lr)*136 + ks*32 + lg*8]);
      #pragma unroll
      for (int tt = 0; tt < 4; ++tt){
        int vrow = tt*16 + lr;
        bf16x8 vf = *reinterpret_cast<const bf16x8*>(&Vt[vrow*128 + 8*((ks*4 + lg) ^ (vrow & 15))]);
        oacc[tt] = __builtin_amdgcn_mfma_f32_16x16x32_bf16(pa, vf, oacc[tt], 0, 0, 0);
      }
    }
  }
  #pragma unroll
  for (int tt = 0; tt < 4; ++tt){
    #pragma unroll
    for (int e = 0; e < 4; ++e){
      int q = q0 + w*16 + lg*4 + e;
      int hd = tt*16 + lr;
      ao[((size_t)(b*SEQ + q))*DM + h*HD + hd] = f2bf(oacc[tt][e] / lrow[e]);
    }
  }
}

extern "C" void kernel_launch(void* const* d_in, const int* in_sizes, int n_in,
                              void* d_out, int out_size, void* d_ws, size_t ws_size,
                              hipStream_t stream)
{
  const float* q   = (const float*)d_in[0];
  const float* k   = (const float*)d_in[1];
  const float* v   = (const float*)d_in[2];
  const float* rel = (const float*)d_in[3];
  const float* Wq  = (const float*)d_in[4];
  const float* bq  = (const float*)d_in[5];
  const float* Wk  = (const float*)d_in[6];
  const float* bk  = (const float*)d_in[7];
  const float* Wv  = (const float*)d_in[8];
  const float* bv  = (const float*)d_in[9];
  const float* Wo  = (const float*)d_in[10];
  const float* bo  = (const float*)d_in[11];
  float* out = (float*)d_out;

  char* ws = (char*)d_ws;
  short* qb  = (short*)(ws);
  short* kb  = (short*)(ws + 8388608);
  short* vb  = (short*)(ws + 16777216);
  short* qhb = (short*)(ws + 25165824);
  short* khb = (short*)(ws + 33554432);
  short* vTb = (short*)(ws + 41943040);   // [dm=1024][tok=4096]
  short* aob = (short*)(ws + 50331648);
  short* wqb = (short*)(ws + 58720256);
  short* wkb = (short*)(ws + 60817408);
  short* wvb = (short*)(ws + 62914560);
  short* wob = (short*)(ws + 65011712);
  short* Rs  = (short*)(ws + 67108864);   // [q=1024][bh=64][k=1024] bf16 = 134MB

  dim3 blk(256);
  {
    int big4 = NTOK*DM/4, small4 = DM*DM/4;
    cvt_all<<<dim3(big4/256, 7), blk, 0, stream>>>(q, k, v, Wq, Wk, Wv, Wo,
        qb, kb, vb, wqb, wkb, wvb, wob, big4, small4);
  }
  proj_gemm<<<dim3(NTOK/128, 24), blk, 0, stream>>>(qb, kb, vb, wqb, wkb, wvb,
      bq, bk, bv, qhb, khb, vTb);
  relscore2<<<dim3(SEQ), blk, 0, stream>>>(qhb, rel, Rs);
  flash2<<<dim3(NB*NH, SEQ/64), blk, 0, stream>>>(qhb, khb, vTb, Rs, aob);
  out_gemm<<<dim3(NTOK/128, DM/128), blk, 0, stream>>>(aob, wob, bo, out);
}